// Round 3
// baseline (1251.702 us; speedup 1.0000x reference)
//
#include <hip/hip_runtime.h>
#include <hip/hip_bf16.h>

// Problem constants (fixed by the reference)
#define HEADS 8
#define HID   64
#define EMB   512
#define HH    512      // HEADS*HID
#define LOCAL 64
#define BS    4
#define NSEQ  2048
#define ROWS  (BS*NSEQ)   // 8192

// ---------------------------------------------------------------------------
// Kernel 1: fused Q/K/V projection.  [8192,512] x [512,512] (x3, sharing the
// x tile).  fp32; q,k pre-scaled by 1/8 (ref scales both by d^-0.5).
// ---------------------------------------------------------------------------
__global__ __launch_bounds__(256) void qkv_proj(
    const float* __restrict__ x,
    const float* __restrict__ wq,
    const float* __restrict__ wk,
    const float* __restrict__ wv,
    float* __restrict__ q, float* __restrict__ k, float* __restrict__ v)
{
    __shared__ float xs[16][17], wqs[16][17], wks[16][17], wvs[16][17];
    const int tx = threadIdx.x, ty = threadIdx.y;
    const int col = blockIdx.x * 16 + tx;
    const int row = blockIdx.y * 16 + ty;
    float aq = 0.f, ak = 0.f, av = 0.f;
    for (int kt = 0; kt < EMB; kt += 16) {
        xs [ty][tx] = x [(size_t)row * EMB + kt + tx];
        wqs[ty][tx] = wq[(size_t)(kt + ty) * HH + col];
        wks[ty][tx] = wk[(size_t)(kt + ty) * HH + col];
        wvs[ty][tx] = wv[(size_t)(kt + ty) * HH + col];
        __syncthreads();
#pragma unroll
        for (int i = 0; i < 16; ++i) {
            const float xv = xs[ty][i];
            aq += xv * wqs[i][tx];
            ak += xv * wks[i][tx];
            av += xv * wvs[i][tx];
        }
        __syncthreads();
    }
    const float scale = 0.125f;   // HID^-0.5
    q[(size_t)row * HH + col] = aq * scale;
    k[(size_t)row * HH + col] = ak * scale;
    v[(size_t)row * HH + col] = av;
}

// ---------------------------------------------------------------------------
// Kernel 2: sparse masked attention.  One 64-lane wave per (b, h, qi).
// Allowed keys for query qi (0-based): local window [max(0,qi-64), qi] plus
// strided keys qi - 64*j for j >= 2 (strictly below the window).  <= 95 keys.
// lane = head dim.  Scores via shuffle butterfly reduce; 2-pass softmax.
// o aliases q upstream: each block reads ONLY its own q row slice
// (b,qi,h*HID+lane) before writing that same slice — no cross-block hazard.
// ---------------------------------------------------------------------------
__device__ __forceinline__ int key_of(int idx, int qi, int n_str, int jmax, int kstart) {
    // idx < n_str: strided key with j = jmax - idx  (j runs jmax..2)
    // idx >= n_str: local key kstart + (idx - n_str)
    return (idx < n_str) ? (qi - 64 * (jmax - idx)) : (kstart + (idx - n_str));
}

__global__ __launch_bounds__(64) void attn_sparse(
    const float* __restrict__ q, const float* __restrict__ k,
    const float* __restrict__ v, float* __restrict__ o)
{
    const int bid  = blockIdx.x;          // ((b*NSEQ)+qi)*HEADS + h
    const int h    = bid & (HEADS - 1);
    const int qi   = (bid >> 3) & (NSEQ - 1);
    const int b    = bid >> 14;           // / (HEADS*NSEQ)
    const int lane = threadIdx.x;

    __shared__ float sc[128];

    const size_t rowbase = ((size_t)(b * NSEQ + qi)) * HH + h * HID;
    const float qd = q[rowbase + lane];

    const int jmax   = qi >> 6;
    const int n_str  = (jmax >= 2) ? (jmax - 1) : 0;
    const int kstart = (qi >= LOCAL) ? (qi - LOCAL) : 0;
    const int total  = n_str + (qi - kstart + 1);

    // Pass 1: scores + running max
    float maxv = -INFINITY;
    for (int idx = 0; idx < total; ++idx) {
        const int key = key_of(idx, qi, n_str, jmax, kstart);
        float s = qd * k[((size_t)(b * NSEQ + key)) * HH + h * HID + lane];
#pragma unroll
        for (int off = 32; off; off >>= 1) s += __shfl_xor(s, off, 64);
        if (lane == 0) sc[idx] = s;
        maxv = fmaxf(maxv, s);
    }
    __syncthreads();

    // Pass 2: exp, sum, weighted V accumulate (each lane owns one dim)
    float sum = 0.f, acc = 0.f;
    for (int idx = 0; idx < total; ++idx) {
        const int key = key_of(idx, qi, n_str, jmax, kstart);
        const float p = __expf(sc[idx] - maxv);
        sum += p;
        acc += p * v[((size_t)(b * NSEQ + key)) * HH + h * HID + lane];
    }
    o[rowbase + lane] = acc / sum;
}

// ---------------------------------------------------------------------------
// Kernel 3: unify projection + bias.  [8192,512] x [512,512] + b -> fp32 out.
// ---------------------------------------------------------------------------
__global__ __launch_bounds__(256) void unify(
    const float* __restrict__ a, const float* __restrict__ w,
    const float* __restrict__ bias, float* __restrict__ out)
{
    __shared__ float as[16][17], ws[16][17];
    const int tx = threadIdx.x, ty = threadIdx.y;
    const int col = blockIdx.x * 16 + tx;
    const int row = blockIdx.y * 16 + ty;
    float acc = 0.f;
    for (int kt = 0; kt < HH; kt += 16) {
        as[ty][tx] = a[(size_t)row * HH + kt + tx];
        ws[ty][tx] = w[(size_t)(kt + ty) * EMB + col];
        __syncthreads();
#pragma unroll
        for (int i = 0; i < 16; ++i) acc += as[ty][i] * ws[i][tx];
        __syncthreads();
    }
    out[(size_t)row * EMB + col] = acc + bias[col];
}

// ---------------------------------------------------------------------------
extern "C" void kernel_launch(void* const* d_in, const int* in_sizes, int n_in,
                              void* d_out, int out_size, void* d_ws, size_t ws_size,
                              hipStream_t stream)
{
    // setup_inputs() dict order: x, w_keys, w_queries, w_values, w_unify, b_unify
    const float* x  = (const float*)d_in[0];
    const float* wk = (const float*)d_in[1];
    const float* wq = (const float*)d_in[2];
    const float* wv = (const float*)d_in[3];
    const float* wu = (const float*)d_in[4];
    const float* bu = (const float*)d_in[5];
    float* out = (float*)d_out;

    // fp32 scratch: q, k, v  (3 x 16 MB = 48 MB); attn out aliases q (safe:
    // each attn block reads only its own q row slice before overwriting it).
    float* q = (float*)d_ws;
    float* k = q + (size_t)ROWS * HH;
    float* v = k + (size_t)ROWS * HH;
    float* o = q;

    dim3 blk(16, 16);
    qkv_proj<<<dim3(HH / 16, ROWS / 16), blk, 0, stream>>>(x, wq, wk, wv, q, k, v);
    attn_sparse<<<ROWS * HEADS, 64, 0, stream>>>(q, k, v, o);
    unify<<<dim3(EMB / 16, ROWS / 16), blk, 0, stream>>>(o, wu, bu, out);
}

// Round 4
// 256.753 us; speedup vs baseline: 4.8751x; 4.8751x over previous
//
#include <hip/hip_runtime.h>
#include <hip/hip_bf16.h>

// Problem constants (fixed by the reference)
#define HEADS 8
#define HID   64
#define EMB   512
#define HH    512
#define LOCAL 64
#define BS    4
#define NSEQ  2048
#define ROWS  (BS*NSEQ)   // 8192

typedef __attribute__((ext_vector_type(8))) short short8;   // 8 bf16 = 4 VGPRs
typedef __attribute__((ext_vector_type(4))) float f32x4;    // MFMA acc

// fp32 -> bf16 bits, round-to-nearest-even
__device__ __forceinline__ ushort f2b(float f) {
    union { float f; unsigned u; } c; c.f = f;
    return (ushort)((c.u + 0x7FFFu + ((c.u >> 16) & 1u)) >> 16);
}

// ---------------------------------------------------------------------------
// Convert kernels (tiny): x -> bf16; weights -> bf16 TRANSPOSED (n-major)
// ---------------------------------------------------------------------------
__global__ __launch_bounds__(256) void f2b_vec(const float* __restrict__ in,
                                               ushort* __restrict__ out, int n4) {
    int i = blockIdx.x * 256 + threadIdx.x;
    if (i >= n4) return;
    float4 f = ((const float4*)in)[i];
    ushort4 u;
    u.x = f2b(f.x); u.y = f2b(f.y); u.z = f2b(f.z); u.w = f2b(f.w);
    ((ushort4*)out)[i] = u;
}

// in: [512][512] fp32 (k-major).  out[n][k] = bf16(in[k][n])
__global__ __launch_bounds__(256) void transpose_f2b(const float* __restrict__ in,
                                                     ushort* __restrict__ out) {
    __shared__ float s[16][17];
    const int k0 = blockIdx.y * 16, n0 = blockIdx.x * 16;
    const int tx = threadIdx.x, ty = threadIdx.y;
    s[ty][tx] = in[(size_t)(k0 + ty) * 512 + n0 + tx];
    __syncthreads();
    out[(size_t)(n0 + ty) * 512 + k0 + tx] = f2b(s[tx][ty]);
}

// ---------------------------------------------------------------------------
// MFMA GEMM: C[128x128 tile] = A[ROWS][512](bf16) x Bt[N][512](bf16,n-major)
// 256 thr = 4 waves (2x2), each wave 64x64 via 4x4 of 16x16x32 bf16 MFMA.
// MODE 0: split into q/k/v fp32, scale q,k by 0.125.  MODE 1: +bias -> out.
// Fragment layouts (HW-verified per guide):
//   A: lane holds A[m=lane&15][k=(lane>>4)*8+j]      (8 contig bf16)
//   B: lane holds B[k=(lane>>4)*8+j][n=lane&15]      (contig in Bt[n][k])
//   D: D[row=(lane>>4)*4+reg][col=lane&15]
// ---------------------------------------------------------------------------
template <int MODE>
__global__ __launch_bounds__(256) void gemm_mfma(
    const ushort* __restrict__ A, const ushort* __restrict__ Bt,
    float* __restrict__ q, float* __restrict__ k, float* __restrict__ v,
    const float* __restrict__ bias, float* __restrict__ out)
{
    __shared__ ushort As[128][40];   // +8 pad: 80B row stride -> 2-way (free)
    __shared__ ushort Bs[128][40];
    const int tid  = threadIdx.x;
    const int rowB = blockIdx.y * 128;
    const int colB = blockIdx.x * 128;
    const int wave = tid >> 6, lane = tid & 63;
    const int wm = wave & 1, wn = wave >> 1;
    const int l15 = lane & 15, quad = lane >> 4;
    const int sr = tid >> 1, scol = (tid & 1) * 16;   // staging: row, col-half

    f32x4 acc[4][4] = {};

    for (int kt = 0; kt < EMB; kt += 32) {
        const ushort* ga = A  + (size_t)(rowB + sr) * EMB + kt + scol;
        const ushort* gb = Bt + (size_t)(colB + sr) * EMB + kt + scol;
        *(short8*)&As[sr][scol]     = *(const short8*)ga;
        *(short8*)&As[sr][scol + 8] = *(const short8*)(ga + 8);
        *(short8*)&Bs[sr][scol]     = *(const short8*)gb;
        *(short8*)&Bs[sr][scol + 8] = *(const short8*)(gb + 8);
        __syncthreads();

        short8 af[4], bf[4];
#pragma unroll
        for (int mi = 0; mi < 4; ++mi)
            af[mi] = *(const short8*)&As[wm * 64 + mi * 16 + l15][quad * 8];
#pragma unroll
        for (int ni = 0; ni < 4; ++ni)
            bf[ni] = *(const short8*)&Bs[wn * 64 + ni * 16 + l15][quad * 8];
#pragma unroll
        for (int mi = 0; mi < 4; ++mi)
#pragma unroll
            for (int ni = 0; ni < 4; ++ni)
                acc[mi][ni] = __builtin_amdgcn_mfma_f32_16x16x32_bf16(
                    af[mi], bf[ni], acc[mi][ni], 0, 0, 0);
        __syncthreads();
    }

#pragma unroll
    for (int mi = 0; mi < 4; ++mi)
#pragma unroll
        for (int ni = 0; ni < 4; ++ni)
#pragma unroll
            for (int r = 0; r < 4; ++r) {
                const int row = rowB + wm * 64 + mi * 16 + quad * 4 + r;
                const int col = colB + wn * 64 + ni * 16 + l15;
                const float val = acc[mi][ni][r];
                if (MODE == 0) {
                    const int sec = col >> 9, c = col & 511;   // uniform per block
                    float* dst = (sec == 0) ? q : (sec == 1) ? k : v;
                    const float s = (sec == 2) ? 1.0f : 0.125f;
                    dst[(size_t)row * HH + c] = val * s;
                } else {
                    out[(size_t)row * EMB + col] = val + bias[col];
                }
            }
}

// ---------------------------------------------------------------------------
// Sparse attention.  One wave per (b,h,qi).  lane = sub(key 0..3)*16 + dgrp.
// 4 keys / iteration, float4 per lane; 4 shuffles score 4 keys at once.
// Keys: strided qi-64j (j=jmax..2) then local window [kstart, qi].  <=95 keys.
// Writes o as bf16 (standard [b][n][h*64+d] layout) = unify's A operand.
// ---------------------------------------------------------------------------
__global__ __launch_bounds__(64) void attn_sparse(
    const float* __restrict__ q, const float* __restrict__ k,
    const float* __restrict__ v, ushort* __restrict__ o)
{
    const int bid  = blockIdx.x;                  // ((b*NSEQ)+qi)*HEADS + h
    const int h    = bid & (HEADS - 1);
    const int qi   = (bid >> 3) & (NSEQ - 1);
    const int b    = bid >> 14;
    const int lane = threadIdx.x, dgrp = lane & 15, sub = lane >> 4;

    __shared__ float sc[96];

    const size_t rowbase = ((size_t)(b * NSEQ + qi)) * HH + h * HID;
    const float4 qv = ((const float4*)(q + rowbase))[dgrp];

    const int jmax   = qi >> 6;
    const int n_str  = (jmax >= 2) ? (jmax - 1) : 0;
    const int kstart = (qi >= LOCAL) ? (qi - LOCAL) : 0;
    const int total  = n_str + (qi - kstart + 1);
    const size_t bh  = (size_t)b * NSEQ * HH + h * HID;   // + key*HH

    // Pass 1: scores (4 keys/iter) + running max
    float maxv = -INFINITY;
    for (int base = 0; base < total; base += 4) {
        const int idx  = base + sub;
        const int idxc = (idx < total) ? idx : (total - 1);
        const int key  = (idxc < n_str) ? (qi - 64 * (jmax - idxc))
                                        : (kstart + (idxc - n_str));
        const float4 kv = ((const float4*)(k + bh + (size_t)key * HH))[dgrp];
        float s = qv.x * kv.x + qv.y * kv.y + qv.z * kv.z + qv.w * kv.w;
        s += __shfl_xor(s, 1); s += __shfl_xor(s, 2);
        s += __shfl_xor(s, 4); s += __shfl_xor(s, 8);
        if (idx >= total) s = -INFINITY;
        maxv = fmaxf(maxv, s);
        if (idx < total && dgrp == 0) sc[idx] = s;
    }
    maxv = fmaxf(maxv, __shfl_xor(maxv, 16));
    maxv = fmaxf(maxv, __shfl_xor(maxv, 32));
    __syncthreads();

    // Pass 2: p = exp(s-max); acc4 += p * v4  (4 keys/iter, no in-loop shuffles)
    float ax = 0.f, ay = 0.f, az = 0.f, aw = 0.f, sum = 0.f;
    for (int base = 0; base < total; base += 4) {
        const int idx  = base + sub;
        const int idxc = (idx < total) ? idx : (total - 1);
        const int key  = (idxc < n_str) ? (qi - 64 * (jmax - idxc))
                                        : (kstart + (idxc - n_str));
        const float p = (idx < total) ? __expf(sc[idx] - maxv) : 0.f;
        const float4 vv = ((const float4*)(v + bh + (size_t)key * HH))[dgrp];
        ax += p * vv.x; ay += p * vv.y; az += p * vv.z; aw += p * vv.w;
        sum += p;
    }
    sum += __shfl_xor(sum, 16); sum += __shfl_xor(sum, 32);
    ax += __shfl_xor(ax, 16); ax += __shfl_xor(ax, 32);
    ay += __shfl_xor(ay, 16); ay += __shfl_xor(ay, 32);
    az += __shfl_xor(az, 16); az += __shfl_xor(az, 32);
    aw += __shfl_xor(aw, 16); aw += __shfl_xor(aw, 32);

    if (sub == 0) {
        const float rinv = 1.0f / sum;
        ushort4 u;
        u.x = f2b(ax * rinv); u.y = f2b(ay * rinv);
        u.z = f2b(az * rinv); u.w = f2b(aw * rinv);
        *(ushort4*)(o + rowbase + dgrp * 4) = u;
    }
}

// ---------------------------------------------------------------------------
extern "C" void kernel_launch(void* const* d_in, const int* in_sizes, int n_in,
                              void* d_out, int out_size, void* d_ws, size_t ws_size,
                              hipStream_t stream)
{
    // dict order: x, w_keys, w_queries, w_values, w_unify, b_unify (all fp32)
    const float* x  = (const float*)d_in[0];
    const float* wk = (const float*)d_in[1];
    const float* wq = (const float*)d_in[2];
    const float* wv = (const float*)d_in[3];
    const float* wu = (const float*)d_in[4];
    const float* bu = (const float*)d_in[5];
    float* out = (float*)d_out;

    // Workspace (66 MB): xb | wbt(q,k,v n-major) | wubt | ob | q | k | v
    ushort* xb   = (ushort*)d_ws;                 // ROWS*EMB bf16      (8 MB)
    ushort* wbt  = xb   + (size_t)ROWS * EMB;     // 1536*512 bf16     (1.5 MB)
    ushort* wubt = wbt  + (size_t)1536 * 512;     // 512*512 bf16      (0.5 MB)
    ushort* ob   = wubt + (size_t)512 * 512;      // ROWS*HH bf16       (8 MB)
    float*  q    = (float*)(ob + (size_t)ROWS * HH);
    float*  kk   = q  + (size_t)ROWS * HH;
    float*  vv   = kk + (size_t)ROWS * HH;

    const int n4 = ROWS * EMB / 4;
    f2b_vec<<<(n4 + 255) / 256, 256, 0, stream>>>(x, xb, n4);
    dim3 tb(16, 16), tg(32, 32);
    transpose_f2b<<<tg, tb, 0, stream>>>(wq, wbt);                    // cols 0..511
    transpose_f2b<<<tg, tb, 0, stream>>>(wk, wbt + (size_t)512 * 512);
    transpose_f2b<<<tg, tb, 0, stream>>>(wv, wbt + (size_t)1024 * 512);
    transpose_f2b<<<tg, tb, 0, stream>>>(wu, wubt);

    gemm_mfma<0><<<dim3(1536 / 128, ROWS / 128), 256, 0, stream>>>(
        xb, wbt, q, kk, vv, nullptr, nullptr);
    attn_sparse<<<ROWS * HEADS, 64, 0, stream>>>(q, kk, vv, ob);
    gemm_mfma<1><<<dim3(EMB / 128, ROWS / 128), 256, 0, stream>>>(
        ob, wubt, nullptr, nullptr, nullptr, bu, out);
}